// Round 2
// baseline (2757.891 us; speedup 1.0000x reference)
//
#include <hip/hip_runtime.h>

// ---------------- problem constants ----------------
#define B_     8192
#define D_     32
#define H_     128
#define PH_    64
#define PREP_  10
#define CS_    8
#define CH_    32
#define NT_    16
#define NO_    4096
#define NPOST_ 4
#define DT_    0.1f
#define TWO_LOGC 1.8378770664093453f   // 2*log(sqrt(2*pi))

// ---------------- bf16 fragment-blob offsets (ushort elements) ----------------
// blob layout for a KxN weight: element ((kc*ntiles+nt)*64+lane)*8+j holds
// W[kc*32 + 4*((lane>>4)&3) + (j&3) + 16*(j>>2)][nt*16 + (lane&15)]
#define OFF_XZ   0        // 64x128
#define OFF_HZ   8192     // 128x128
#define OFF_XN   24576
#define OFF_HN   32768
#define OFF_PW1  49152    // 128x64
#define OFF_PW2  57344    // 64x64
#define OFF_WIHR 61440    // 320x128 per gate
#define OFF_WIHZ 102400
#define OFF_WIHN 143360
#define OFF_WHHR 184320   // 128x128 per gate
#define OFF_WHHZ 200704
#define OFF_WHHN 217088
#define BLOB_ELEMS 233472
#define INV_BYTE_OFF ((size_t)BLOB_ELEMS*2)

// activation LDS strides (ushorts); strides are 16B multiples with
// (stride_dwords % 8) == 4 so ds_read_b128 fragment reads hit the bank floor
#define STRH 136
#define STRP 72
#define STRG 328
#define AOFF_HB   0
#define AOFF_ZH   2176
#define AOFF_PB   4352
#define AOFF_QB   5504
#define AOFF_GIN  6656
#define ACT_W     11904

// shared fp32 constant table offsets (floats)
#define SB_XZ    0
#define SB_XN    128
#define SB_P1    256
#define SB_P2    320
#define SB_BRZ   384      // b_ih+b_hh for r (0..127) and z (128..255)
#define SB_BIN   640      // b_ih n-chunk
#define SB_BHN   768      // b_hh n-chunk
#define SB_WPREP 896      // 1280
#define SB_BPREP 2176     // 320
#define SB_TOT   2496

typedef float f4  __attribute__((ext_vector_type(4)));
typedef short bf8 __attribute__((ext_vector_type(8)));

__device__ __forceinline__ f4 mfma16(bf8 a, bf8 b, f4 c){
  return __builtin_amdgcn_mfma_f32_16x16x32_bf16(a,b,c,0,0,0);
}
__device__ __forceinline__ unsigned short f2bf(float f){
  unsigned int u = __builtin_bit_cast(unsigned int, f);
  u = (u + 0x7FFFu + ((u>>16)&1u)) >> 16;
  return (unsigned short)u;
}
__device__ __forceinline__ float sigmoidf_(float x){ return 1.f/(1.f+__expf(-x)); }
// column k -> ushort position inside a swizzled activation row: fragment order
__device__ __forceinline__ int permk(int k){
  return ((k>>5)<<5) | (((k>>2)&3)<<3) | (((k>>4)&1)<<2) | (k&3);
}

// 16xK @ KxN GEMM; A from wave-private swizzled LDS (one b128/lane/kc),
// B fragments streamed directly from global (L2-resident blob).
template<int NKC,int NT>
__device__ __forceinline__ void gemmG(f4* acc, const unsigned short* Ald, int strideUsh,
                                      const unsigned short* __restrict__ Bg, int lane){
  const unsigned short* arow = Ald + (lane&15)*strideUsh + (lane>>4)*8;
  const unsigned short* bl   = Bg + lane*8;
  #pragma unroll
  for(int kc=0;kc<NKC;kc++){
    bf8 av = *(const bf8*)(arow + kc*32);
    #pragma unroll
    for(int nt=0;nt<NT;nt++){
      bf8 bv = *(const bf8*)(bl + (kc*NT+nt)*512);
      acc[nt] = mfma16(av, bv, acc[nt]);
    }
  }
}

template<int NT>
__device__ __forceinline__ void initacc(f4* acc, const float* b, int lc){
  #pragma unroll
  for(int nt=0;nt<NT;nt++){ float v = b[nt*16+lc]; f4 t = {v,v,v,v}; acc[nt]=t; }
}

// ---------------- prep kernels ----------------
__global__ void init_inv(unsigned short* inv, float* outLoss){
  int i = blockIdx.x*256 + threadIdx.x;
  if(i < NT_*B_) inv[i] = 0xFFFFu;
  if(i == 0) *outLoss = 0.f;
}

__global__ void scatter_inv(unsigned short* inv, const int* __restrict__ obs){
  int i = blockIdx.x*256 + threadIdx.x;
  if(i < NT_*NO_){
    int t = i >> 12;
    int o = i & 4095;
    inv[(size_t)t*B_ + obs[i]] = (unsigned short)o;
  }
}

__global__ void build_blobs(const float* __restrict__ pw1, const float* __restrict__ pw2,
                            const float* __restrict__ xzw, const float* __restrict__ hzw,
                            const float* __restrict__ xnw, const float* __restrict__ hnw,
                            const float* __restrict__ wih, const float* __restrict__ whh,
                            unsigned short* __restrict__ blob){
  int sec = blockIdx.y;
  int e = blockIdx.x*256 + threadIdx.x;
  const float* src; int Ksrc, N, ld, col0, off, cnt;
  switch(sec){
    case 0:  src=xzw; Ksrc=64;  N=128; ld=128; col0=0; off=OFF_XZ;  cnt=8192;  break;
    case 1:  src=hzw; Ksrc=128; N=128; ld=128; col0=0; off=OFF_HZ;  cnt=16384; break;
    case 2:  src=xnw; Ksrc=64;  N=128; ld=128; col0=0; off=OFF_XN;  cnt=8192;  break;
    case 3:  src=hnw; Ksrc=128; N=128; ld=128; col0=0; off=OFF_HN;  cnt=16384; break;
    case 4:  src=pw1; Ksrc=128; N=64;  ld=64;  col0=0; off=OFF_PW1; cnt=8192;  break;
    case 5:  src=pw2; Ksrc=64;  N=64;  ld=64;  col0=0; off=OFF_PW2; cnt=4096;  break;
    case 6: case 7: case 8: {
      int g = sec-6; src=wih; Ksrc=320; N=128; ld=384; col0=g*128;
      off=OFF_WIHR + g*40960; cnt=40960; } break;
    default: {
      int g = sec-9; src=whh; Ksrc=128; N=128; ld=384; col0=g*128;
      off=OFF_WHHR + g*16384; cnt=16384; } break;
  }
  if(e >= cnt) return;
  int ntiles = N >> 4;
  int perkc = ntiles << 9;
  int kc = e / perkc, rem = e % perkc;
  int nt = rem >> 9, li = rem & 511;
  int lane = li >> 3, j = li & 7;
  int n = nt*16 + (lane & 15);
  int k = kc*32 + ((lane>>4)&3)*4 + (j&3) + ((j>>2)<<4);
  float v = (k < Ksrc) ? src[(size_t)k*ld + col0 + n] : 0.f;
  blob[off + e] = f2bf(v);
}

// ---------------- fused persistent kernel: 2 independent waves/block ----------------
__global__ __launch_bounds__(128,1) void fused(
    const float* __restrict__ X, const float* __restrict__ M,
    const float* __restrict__ cov,
    const float* __restrict__ cm_w1, const float* __restrict__ cm_b1,
    const float* __restrict__ cm_w2, const float* __restrict__ cm_b2,
    const float* __restrict__ p_b1, const float* __restrict__ p_b2,
    const float* __restrict__ xz_b, const float* __restrict__ xn_b,
    const float* __restrict__ b_ih, const float* __restrict__ b_hh,
    const float* __restrict__ w_prep, const float* __restrict__ bias_prep,
    const unsigned short* __restrict__ blob, const unsigned short* __restrict__ inv,
    float* __restrict__ outH, float* __restrict__ outP, float* __restrict__ outLoss)
{
  __shared__ __align__(16) unsigned short act[2*ACT_W];
  __shared__ float sb[SB_TOT];
  __shared__ float hInit[32][132];
  __shared__ float c1s[32][36];

  const int tid  = threadIdx.x;
  const int lane = tid & 63;
  const int w    = tid >> 6;
  const int lc   = lane & 15;
  const int a4   = lane >> 4;          // 0..3
  const int base = blockIdx.x*32 + w*16;
  float lsum = 0.f;

  unsigned short* hb  = act + w*ACT_W + AOFF_HB;
  unsigned short* zh  = act + w*ACT_W + AOFF_ZH;
  unsigned short* pb  = act + w*ACT_W + AOFF_PB;
  unsigned short* qb  = act + w*ACT_W + AOFF_QB;
  unsigned short* gin = act + w*ACT_W + AOFF_GIN;

  // ---- stage fp32 constants ----
  for(int i=tid;i<128;i+=128){ sb[SB_XZ+i]=xz_b[i]; sb[SB_XN+i]=xn_b[i];
                               sb[SB_BIN+i]=b_ih[256+i]; sb[SB_BHN+i]=b_hh[256+i]; }
  for(int i=tid;i<64;i+=128){ sb[SB_P1+i]=p_b1[i]; sb[SB_P2+i]=p_b2[i]; }
  for(int i=tid;i<256;i+=128) sb[SB_BRZ+i]=b_ih[i]+b_hh[i];
  for(int i=tid;i<1280;i+=128) sb[SB_WPREP+i]=w_prep[i];
  for(int i=tid;i<320;i+=128) sb[SB_BPREP+i]=bias_prep[i];

  // ---- init h = tanh(relu(cov@cm_w1+b1)@cm_w2+b2) (one-time scalar path) ----
  {
    int row = tid>>2, q = tid&3;
    float a[8];
    #pragma unroll
    for(int j=0;j<8;j++) a[j]=cm_b1[q*8+j];
    #pragma unroll
    for(int k=0;k<CS_;k++){
      float cv = cov[(size_t)(blockIdx.x*32+row)*CS_+k];
      #pragma unroll
      for(int j=0;j<8;j++) a[j] += cv*cm_w1[k*CH_+q*8+j];
    }
    #pragma unroll
    for(int j=0;j<8;j++) c1s[row][q*8+j] = fmaxf(a[j],0.f);
    __syncthreads();
    float acc2[32];
    #pragma unroll
    for(int j=0;j<32;j++) acc2[j]=cm_b2[q*32+j];
    for(int k=0;k<CH_;k++){
      float cv = c1s[row][k];
      #pragma unroll
      for(int j=0;j<32;j++) acc2[j] += cv*cm_w2[k*H_+q*32+j];
    }
    #pragma unroll
    for(int j=0;j<32;j++) hInit[row][q*32+j] = tanhf(acc2[j]);
    __syncthreads();
  }

  f4 hFr[8], pFr[4];
  #pragma unroll
  for(int nt=0;nt<8;nt++)
    #pragma unroll
    for(int g=0;g<4;g++){
      float v = hInit[w*16 + a4*4+g][nt*16+lc];
      hFr[nt][g]=v;
      hb[(a4*4+g)*STRH + permk(nt*16+lc)] = f2bf(v);
    }

  // ---- p_model ----
  auto pmodel = [&](){
    f4 q[4]; initacc<4>(q, sb+SB_P1, lc);
    gemmG<4,4>(q, hb, STRH, blob+OFF_PW1, lane);
    #pragma unroll
    for(int nt=0;nt<4;nt++)
      #pragma unroll
      for(int g=0;g<4;g++)
        qb[(a4*4+g)*STRP + permk(nt*16+lc)] = f2bf(fmaxf(q[nt][g],0.f));
    f4 p[4]; initacc<4>(p, sb+SB_P2, lc);
    gemmG<2,4>(p, qb, STRP, blob+OFF_PW2, lane);
    #pragma unroll
    for(int nt=0;nt<4;nt++){
      pFr[nt]=p[nt];
      #pragma unroll
      for(int g=0;g<4;g++)
        pb[(a4*4+g)*STRP + permk(nt*16+lc)] = f2bf(p[nt][g]);
    }
  };

  // ---- euler step ----
  auto euler = [&](){
    f4 az[8]; initacc<8>(az, sb+SB_XZ, lc);
    gemmG<2,8>(az, pb, STRP, blob+OFF_XZ, lane);
    gemmG<4,8>(az, hb, STRH, blob+OFF_HZ, lane);
    f4 zr[8];
    #pragma unroll
    for(int nt=0;nt<8;nt++)
      #pragma unroll
      for(int g=0;g<4;g++){
        float z = sigmoidf_(az[nt][g]);
        zr[nt][g]=z;
        zh[(a4*4+g)*STRH + permk(nt*16+lc)] = f2bf(z*hFr[nt][g]);
      }
    f4 an[8]; initacc<8>(an, sb+SB_XN, lc);
    gemmG<2,8>(an, pb, STRP, blob+OFF_XN, lane);
    gemmG<4,8>(an, zh, STRH, blob+OFF_HN, lane);
    #pragma unroll
    for(int nt=0;nt<8;nt++)
      #pragma unroll
      for(int g=0;g<4;g++){
        float nn = tanhf(an[nt][g]);
        float ho = hFr[nt][g];
        float hv = ho + DT_*(1.f-zr[nt][g])*(nn-ho);
        hFr[nt][g]=hv;
        hb[(a4*4+g)*STRH + permk(nt*16+lc)] = f2bf(hv);
      }
  };

  // ---- Bayesian jump ----
  auto jump = [&](int t){
    int og[4];
    #pragma unroll
    for(int g=0;g<4;g++){
      unsigned short v = inv[(size_t)t*B_ + base + a4*4 + g];
      og[g] = (v==0xFFFFu)? -1 : (int)v;
    }
    #pragma unroll
    for(int g=0;g<4;g++){
      int row = a4*4+g;
      int o = og[g];
      #pragma unroll
      for(int half=0; half<2; half++){
        int d = half*16 + lc;
        float xa=0.f, ma=0.f;
        if(o>=0){
          const float* Xr = X + ((size_t)t*NO_+o)*D_;
          const float* Mr = M + ((size_t)t*NO_+o)*D_;
          xa = Xr[d]; ma = Mr[d];
        }
        float mean = pFr[half][g];     // col d     -> tile half
        float lv   = pFr[2+half][g];   // col 32+d  -> tile 2+half
        float sg = __expf(0.5f*lv);
        float er = (xa-mean)/sg;
        if(ma>0.f) lsum += 0.5f*(er*er + lv + TWO_LOGC);
        const float* wp = sb + SB_WPREP + d*4*PREP_;
        const float* bpv= sb + SB_BPREP + d*PREP_;
        #pragma unroll
        for(int pr=0;pr<PREP_;pr++){
          float s = xa*wp[pr] + mean*wp[PREP_+pr] + lv*wp[2*PREP_+pr] + er*wp[3*PREP_+pr] + bpv[pr];
          s = fmaxf(s,0.f);
          float sv = (ma>0.f)? s : 0.f;
          gin[row*STRG + permk(d*PREP_+pr)] = f2bf(sv);
        }
      }
    }
    // r gate
    f4 rA[8]; initacc<8>(rA, sb+SB_BRZ, lc);
    gemmG<10,8>(rA, gin, STRG, blob+OFF_WIHR, lane);
    gemmG<4,8> (rA, hb,  STRH, blob+OFF_WHHR, lane);
    f4 rv[8];
    #pragma unroll
    for(int nt=0;nt<8;nt++)
      #pragma unroll
      for(int g=0;g<4;g++) rv[nt][g] = sigmoidf_(rA[nt][g]);
    // z gate
    f4 zA[8]; initacc<8>(zA, sb+SB_BRZ+128, lc);
    gemmG<10,8>(zA, gin, STRG, blob+OFF_WIHZ, lane);
    gemmG<4,8> (zA, hb,  STRH, blob+OFF_WHHZ, lane);
    // n gate (keep gi, gh separate: n = tanh(gi + r*gh))
    f4 giA[8]; initacc<8>(giA, sb+SB_BIN, lc);
    gemmG<10,8>(giA, gin, STRG, blob+OFF_WIHN, lane);
    f4 ghA[8]; initacc<8>(ghA, sb+SB_BHN, lc);
    gemmG<4,8> (ghA, hb,  STRH, blob+OFF_WHHN, lane);
    #pragma unroll
    for(int nt=0;nt<8;nt++)
      #pragma unroll
      for(int g=0;g<4;g++){
        float nn = tanhf(giA[nt][g] + rv[nt][g]*ghA[nt][g]);
        float zz = sigmoidf_(zA[nt][g]);
        float hv = (1.f-zz)*nn + zz*hFr[nt][g];
        if(og[g]>=0){
          hFr[nt][g]=hv;
          hb[(a4*4+g)*STRH + permk(nt*16+lc)] = f2bf(hv);
        }
      }
  };

  // ---- sequence ----
  pmodel();
  for(int t=0;t<NT_;t++){
    euler();
    pmodel();
    jump(t);
    pmodel();
  }
  for(int it=0;it<NPOST_;it++){
    euler();
    pmodel();
  }

  // ---- outputs ----
  #pragma unroll
  for(int nt=0;nt<8;nt++)
    #pragma unroll
    for(int g=0;g<4;g++)
      outH[(size_t)(base + a4*4+g)*H_ + nt*16+lc] = hFr[nt][g];
  #pragma unroll
  for(int nt=0;nt<4;nt++)
    #pragma unroll
    for(int g=0;g<4;g++)
      outP[(size_t)(base + a4*4+g)*(2*D_) + nt*16+lc] = pFr[nt][g];

  #pragma unroll
  for(int off=32;off>0;off>>=1) lsum += __shfl_down(lsum, off);
  if(lane==0) atomicAdd(outLoss, lsum);
}

// ---------------- launcher ----------------
extern "C" void kernel_launch(void* const* d_in, const int* in_sizes, int n_in,
                              void* d_out, int out_size, void* d_ws, size_t ws_size,
                              hipStream_t stream){
  const float* X      = (const float*)d_in[0];
  const float* M      = (const float*)d_in[1];
  const int*   obs    = (const int*)  d_in[2];
  const float* cov    = (const float*)d_in[3];
  const float* cm_w1  = (const float*)d_in[4];
  const float* cm_b1  = (const float*)d_in[5];
  const float* cm_w2  = (const float*)d_in[6];
  const float* cm_b2  = (const float*)d_in[7];
  const float* p_w1   = (const float*)d_in[8];
  const float* p_b1   = (const float*)d_in[9];
  const float* p_w2   = (const float*)d_in[10];
  const float* p_b2   = (const float*)d_in[11];
  const float* xz_w   = (const float*)d_in[12];
  const float* xz_b   = (const float*)d_in[13];
  const float* hz_w   = (const float*)d_in[14];
  const float* xn_w   = (const float*)d_in[15];
  const float* xn_b   = (const float*)d_in[16];
  const float* hn_w   = (const float*)d_in[17];
  const float* w_ih   = (const float*)d_in[18];
  const float* w_hh   = (const float*)d_in[19];
  const float* b_ih   = (const float*)d_in[20];
  const float* b_hh   = (const float*)d_in[21];
  const float* w_prep = (const float*)d_in[22];
  const float* bprep  = (const float*)d_in[23];

  unsigned short* blob = (unsigned short*)d_ws;
  unsigned short* inv  = (unsigned short*)((char*)d_ws + INV_BYTE_OFF);
  float* outH = (float*)d_out;
  float* outP = outH + (size_t)B_*H_;
  float* outLoss = outP + (size_t)B_*2*D_;

  init_inv   <<<dim3((NT_*B_+255)/256), dim3(256), 0, stream>>>(inv, outLoss);
  scatter_inv<<<dim3((NT_*NO_+255)/256), dim3(256), 0, stream>>>(inv, obs);
  build_blobs<<<dim3(160,12), dim3(256), 0, stream>>>(p_w1,p_w2,xz_w,hz_w,xn_w,hn_w,w_ih,w_hh, blob);
  fused      <<<dim3(B_/32), dim3(128), 0, stream>>>(
      X, M, cov, cm_w1, cm_b1, cm_w2, cm_b2, p_b1, p_b2, xz_b, xn_b,
      b_ih, b_hh, w_prep, bprep, blob, inv, outH, outP, outLoss);
}